// Round 2
// baseline (203.892 us; speedup 1.0000x reference)
//
#include <hip/hip_runtime.h>
#include <hip/hip_bf16.h>

// MeanEmbedding: out[b,d] = (1/len[b]) * sum_{s<len[b]} xs[b,s,d]
// xs: [B=16, S=4096, D=512] fp32, xs_len: [B] int, out: [B, D] fp32.
//
// Two-phase deterministic reduction (no atomics, no output memset):
//  Phase 1: grid (B, C=128) x 128 thr. Each block sums a 32-row slab across
//           the full D width (128 lanes x float4, coalesced 16 B/lane) and
//           writes a partial [D] vector to d_ws. Fully-masked slabs exit.
//  Phase 2: B blocks x 128 thr. Each lane sums the <=128 active partials for
//           its float4 column, scales by 1/len, writes d_out (covers every
//           element, so the 0xAA poison is fully overwritten).

#define THREADS 128       // D/4 = 128 float4 columns
#define CHUNKS  128       // S/CHUNKS = 32 rows per phase-1 block

__global__ __launch_bounds__(THREADS) void mean_embed_phase1(
    const float* __restrict__ xs,
    const int*   __restrict__ xs_len,
    float*       __restrict__ ws,
    int S, int D)
{
    const int b     = blockIdx.x;
    const int chunk = blockIdx.y;
    const int L     = xs_len[b];

    const int rows = S / CHUNKS;              // 32
    const int row0 = chunk * rows;
    if (row0 >= L) return;                    // slab entirely masked: no write
    const int row1 = min(row0 + rows, L);

    const int tid = threadIdx.x;              // float4 column
    const int d4  = D >> 2;                   // 128

    const float4* base = (const float4*)(xs + (size_t)b * S * D);

    float4 acc = make_float4(0.f, 0.f, 0.f, 0.f);
    #pragma unroll 4
    for (int s = row0; s < row1; ++s) {
        float4 v = base[(size_t)s * d4 + tid];
        acc.x += v.x; acc.y += v.y; acc.z += v.z; acc.w += v.w;
    }

    float4* wsv = (float4*)ws;
    wsv[((size_t)b * CHUNKS + chunk) * d4 + tid] = acc;
}

__global__ __launch_bounds__(THREADS) void mean_embed_phase2(
    const float* __restrict__ ws,
    const int*   __restrict__ xs_len,
    float*       __restrict__ out,
    int S, int D)
{
    const int b   = blockIdx.x;
    const int tid = threadIdx.x;
    const int L   = xs_len[b];
    const int d4  = D >> 2;

    const int rows   = S / CHUNKS;                       // 32
    const int nact   = (L + rows - 1) / rows;            // active chunks

    const float4* wsv = (const float4*)ws;
    float4 acc = make_float4(0.f, 0.f, 0.f, 0.f);
    for (int c = 0; c < nact; ++c) {
        float4 v = wsv[((size_t)b * CHUNKS + c) * d4 + tid];
        acc.x += v.x; acc.y += v.y; acc.z += v.z; acc.w += v.w;
    }

    const float inv = 1.0f / (float)L;
    float4 r = make_float4(acc.x * inv, acc.y * inv, acc.z * inv, acc.w * inv);
    ((float4*)out)[(size_t)b * d4 + tid] = r;
}

extern "C" void kernel_launch(void* const* d_in, const int* in_sizes, int n_in,
                              void* d_out, int out_size, void* d_ws, size_t ws_size,
                              hipStream_t stream) {
    const float* xs     = (const float*)d_in[0];
    const int*   xs_len = (const int*)d_in[1];
    float*       out    = (float*)d_out;
    float*       ws     = (float*)d_ws;

    const int B = in_sizes[1];                 // 16
    const int total = in_sizes[0];             // B*S*D
    const int D = 512;
    const int S = total / (B * D);             // 4096

    dim3 g1(B, CHUNKS);
    mean_embed_phase1<<<g1, THREADS, 0, stream>>>(xs, xs_len, ws, S, D);
    mean_embed_phase2<<<B, THREADS, 0, stream>>>(ws, xs_len, out, S, D);
}